// Round 1
// baseline (7082.499 us; speedup 1.0000x reference)
//
#include <hip/hip_runtime.h>

#define N_IN 2000000
#define N_OUT 250000
#define C_IN 32
#define C_OUT 64
#define K_VOL 8
#define EPS 1e-5f

// ---- workspace layout (bytes) ----
// 0    : int   hist[8]
// 32   : int   bstart[8]   (padded bucket starts, 256-aligned)
// 64   : int   cursor[8]
// 128  : float sums[64]
// 384  : float sumsq[64]
// 640  : float ctx_out[128]   (scale[64], shift[64])
// 1152 : float AB[128]        (A[64], B[64])
// 8192 : int   perm[PERM_CAP]
#define WS_HIST   0
#define WS_BSTART 8
#define WS_CURSOR 16
#define WS_SUMS   (128/4)
#define WS_SUMSQ  (384/4)
#define WS_CTX    (640/4)
#define WS_AB     (1152/4)
#define WS_PERM_BYTES 8192

#define CONV_BLOCKS 7821               // ceil((N_IN + K_VOL*256)/256)
#define PERM_CAP (CONV_BLOCKS*256)     // 2,002,176

__global__ __launch_bounds__(256) void k_hist(const int* __restrict__ offs,
                                              int* __restrict__ hist) {
    __shared__ int lh[K_VOL];
    int t = threadIdx.x;
    if (t < K_VOL) lh[t] = 0;
    __syncthreads();
    int i4 = blockIdx.x * 256 + t;
    if (i4 < N_IN / 4) {
        int4 v = ((const int4*)offs)[i4];
        atomicAdd(&lh[v.x], 1); atomicAdd(&lh[v.y], 1);
        atomicAdd(&lh[v.z], 1); atomicAdd(&lh[v.w], 1);
    }
    __syncthreads();
    if (t < K_VOL) atomicAdd(&hist[t], lh[t]);
}

__global__ void k_scan(int* __restrict__ wsi) {
    if (threadIdx.x == 0) {
        int s = 0;
        for (int k = 0; k < K_VOL; ++k) {
            wsi[WS_BSTART + k] = s;
            wsi[WS_CURSOR + k] = s;
            s += (wsi[WS_HIST + k] + 255) & ~255;
        }
    }
}

__global__ __launch_bounds__(256) void k_scatter(const int* __restrict__ offs,
                                                 int* __restrict__ cursor,
                                                 int* __restrict__ perm) {
    __shared__ int lcnt[K_VOL];
    __shared__ int lbase[K_VOL];
    int t = threadIdx.x;
    if (t < K_VOL) lcnt[t] = 0;
    __syncthreads();
    int i = blockIdx.x * 256 + t;
    int k = 0, lpos = 0;
    bool valid = i < N_IN;
    if (valid) { k = offs[i]; lpos = atomicAdd(&lcnt[k], 1); }
    __syncthreads();
    if (t < K_VOL && lcnt[t] > 0) lbase[t] = atomicAdd(&cursor[t], lcnt[t]);
    __syncthreads();
    if (valid) perm[lbase[k] + lpos] = i;
}

__global__ __launch_bounds__(256) void k_conv(const float* __restrict__ in_feats,
                                              const int* __restrict__ out_idx,
                                              const float* __restrict__ weight,
                                              const int* __restrict__ bstart,
                                              const int* __restrict__ perm,
                                              float* __restrict__ out) {
    int p = blockIdx.x * 256 + threadIdx.x;
    int p0 = blockIdx.x * 256;
    // buckets are 256-aligned -> k uniform per block
    int k = 0;
#pragma unroll
    for (int t = 1; t < K_VOL; ++t)
        if (p0 >= bstart[t]) k = t;
    k = __builtin_amdgcn_readfirstlane(k);
    const float4* __restrict__ Wk = (const float4*)(weight + (size_t)k * (C_IN * C_OUT));

    int idx = perm[p];
    bool valid = idx >= 0;

    float4 xv[8];
#pragma unroll
    for (int q = 0; q < 8; ++q) xv[q] = make_float4(0.f, 0.f, 0.f, 0.f);
    if (valid) {
        const float4* xr = (const float4*)(in_feats + (size_t)idx * C_IN);
#pragma unroll
        for (int q = 0; q < 8; ++q) xv[q] = xr[q];
    }

    float4 acc[16];
#pragma unroll
    for (int c = 0; c < 16; ++c) acc[c] = make_float4(0.f, 0.f, 0.f, 0.f);

#pragma unroll
    for (int j = 0; j < C_IN; ++j) {
        const float4 xq = xv[j >> 2];
        const float xj = ((j & 3) == 0) ? xq.x : ((j & 3) == 1) ? xq.y
                        : ((j & 3) == 2) ? xq.z : xq.w;
#pragma unroll
        for (int c = 0; c < 16; ++c) {
            const float4 w = Wk[j * 16 + c];   // wave-uniform -> s_load
            acc[c].x = fmaf(xj, w.x, acc[c].x);
            acc[c].y = fmaf(xj, w.y, acc[c].y);
            acc[c].z = fmaf(xj, w.z, acc[c].z);
            acc[c].w = fmaf(xj, w.w, acc[c].w);
        }
    }

    if (valid) {
        float* op = out + (size_t)out_idx[idx] * C_OUT;
#pragma unroll
        for (int c = 0; c < 16; ++c) {
            atomicAdd(op + 4 * c + 0, acc[c].x);
            atomicAdd(op + 4 * c + 1, acc[c].y);
            atomicAdd(op + 4 * c + 2, acc[c].z);
            atomicAdd(op + 4 * c + 3, acc[c].w);
        }
    }
}

__global__ __launch_bounds__(256) void k_stats(const float* __restrict__ out,
                                               float* __restrict__ sums,
                                               float* __restrict__ sumsq) {
    int t = threadIdx.x;
    long stride = (long)gridDim.x * 256;   // multiple of 64 -> channel fixed per thread
    float s = 0.f, q = 0.f;
    for (long i = (long)blockIdx.x * 256 + t; i < (long)N_OUT * C_OUT; i += stride) {
        float v = out[i];
        s += v;
        q = fmaf(v, v, q);
    }
    __shared__ float ls[256], lq[256];
    ls[t] = s; lq[t] = q;
    __syncthreads();
    if (t < 64) {
        s = ls[t] + ls[t + 64] + ls[t + 128] + ls[t + 192];
        q = lq[t] + lq[t + 64] + lq[t + 128] + lq[t + 192];
        atomicAdd(&sums[t], s);
        atomicAdd(&sumsq[t], q);
    }
}

__global__ void k_ctx(const float* __restrict__ context,
                      const float* __restrict__ ctx_w,
                      float* __restrict__ ctx_out) {
    int t = threadIdx.x;  // 128 threads
    float s = 0.f;
    for (int r = 0; r < 256; ++r) s = fmaf(context[r], ctx_w[r * 128 + t], s);
    ctx_out[t] = s;
}

__global__ void k_prep(const float* __restrict__ sums, const float* __restrict__ sumsq,
                       const float* __restrict__ gamma, const float* __restrict__ beta,
                       const int* __restrict__ cond, const float* __restrict__ ctx_out,
                       float* __restrict__ AB) {
    int c = threadIdx.x;  // 64 threads
    float mean = sums[c] * (1.f / N_OUT);
    float var  = sumsq[c] * (1.f / N_OUT) - mean * mean;
    float inv  = rsqrtf(var + EPS);
    int cd = cond[0];
    float g = gamma[cd * C_OUT + c], b = beta[cd * C_OUT + c];
    float sc = 1.f + ctx_out[c];
    float sh = ctx_out[64 + c];
    AB[c]      = inv * g * sc;
    AB[64 + c] = (b - mean * inv * g) * sc + sh;
}

__global__ __launch_bounds__(256) void k_norm(float* __restrict__ out,
                                              const float* __restrict__ AB) {
    __shared__ float4 lA[16], lB[16];
    int t = threadIdx.x;
    if (t < 16) {
        lA[t] = ((const float4*)AB)[t];
        lB[t] = ((const float4*)AB)[16 + t];
    }
    __syncthreads();
    const long total4 = (long)N_OUT * C_OUT / 4;
    long stride = (long)gridDim.x * 256;
    for (long i = (long)blockIdx.x * 256 + t; i < total4; i += stride) {
        float4 v = ((float4*)out)[i];
        float4 a = lA[i & 15], b = lB[i & 15];
        v.x = fmaxf(fmaf(v.x, a.x, b.x), 0.f);
        v.y = fmaxf(fmaf(v.y, a.y, b.y), 0.f);
        v.z = fmaxf(fmaf(v.z, a.z, b.z), 0.f);
        v.w = fmaxf(fmaf(v.w, a.w, b.w), 0.f);
        ((float4*)out)[i] = v;
    }
}

extern "C" void kernel_launch(void* const* d_in, const int* in_sizes, int n_in,
                              void* d_out, int out_size, void* d_ws, size_t ws_size,
                              hipStream_t stream) {
    const float* in_feats = (const float*)d_in[0];
    const int*   offs     = (const int*)d_in[1];
    const int*   out_idx  = (const int*)d_in[2];
    const float* weight   = (const float*)d_in[3];
    const float* gamma    = (const float*)d_in[4];
    const float* beta     = (const float*)d_in[5];
    const float* context  = (const float*)d_in[6];
    const float* ctx_w    = (const float*)d_in[7];
    const int*   cond     = (const int*)d_in[8];
    float* out = (float*)d_out;

    int*   wsi  = (int*)d_ws;
    float* wsf  = (float*)d_ws;
    int*   perm = (int*)((char*)d_ws + WS_PERM_BYTES);

    // init: out accumulator = 0, small ws scalars = 0, perm = -1 (pad sentinel)
    hipMemsetAsync(d_out, 0, (size_t)N_OUT * C_OUT * sizeof(float), stream);
    hipMemsetAsync(d_ws, 0, WS_PERM_BYTES, stream);
    hipMemsetAsync(perm, 0xFF, (size_t)PERM_CAP * sizeof(int), stream);

    k_hist<<<(N_IN / 4 + 255) / 256, 256, 0, stream>>>(offs, wsi + WS_HIST);
    k_scan<<<1, 1, 0, stream>>>(wsi);
    k_scatter<<<(N_IN + 255) / 256, 256, 0, stream>>>(offs, wsi + WS_CURSOR, perm);
    k_conv<<<CONV_BLOCKS, 256, 0, stream>>>(in_feats, out_idx, weight,
                                            wsi + WS_BSTART, perm, out);
    k_stats<<<2048, 256, 0, stream>>>(out, wsf + WS_SUMS, wsf + WS_SUMSQ);
    k_ctx<<<1, 128, 0, stream>>>(context, ctx_w, wsf + WS_CTX);
    k_prep<<<1, 64, 0, stream>>>(wsf + WS_SUMS, wsf + WS_SUMSQ, gamma, beta,
                                 cond, wsf + WS_CTX, wsf + WS_AB);
    k_norm<<<2048, 256, 0, stream>>>(out, wsf + WS_AB);
}

// Round 2
// 788.374 us; speedup vs baseline: 8.9837x; 8.9837x over previous
//
#include <hip/hip_runtime.h>

#define N_IN 2000000
#define N_OUT 250000
#define C_IN 32
#define C_OUT 64
#define K_VOL 8
#define EPS 1e-5f

// ================= fast-path workspace layout (int units) =================
// [0]                  : S anchor (always 0)  -> Sarr = wsi, start=Sarr[row], end=Sarr[row+1]
// [1 .. 250112]        : S_base[0..250111]  (exclusive scan; destructively bumped by scatter)
// [250368 .. 266751]   : WT (quad-packed weights, 16384 floats)
// [266752 .. 267775]   : bsum[1024]
// [267776 .. 268159]   : smalls: sums[64], sumsq[64], ctx[128], AB[128]
// [268288 .. 2268287]  : rlist[2M]  (cnt[250112] aliases its head pre-scan)
#define FP_S_PAD     250368
#define FP_WT        250368
#define FP_BSUM      266752
#define FP_SMALL     267776
#define FP_RLIST     268288
#define FP_NEED_BYTES ((size_t)(FP_RLIST + N_IN) * 4)   // 9,073,152 B

#define N_SCAN 250112          // 977*256
#define N_SBLK 977
#define N_GROUPS 31250         // N_OUT/8
#define GCONV_BLOCKS 7813      // ceil(31250/4)
#define PT_BLOCKS 7813         // ceil(N_IN/256)

// ========================= fast path kernels =========================

__global__ __launch_bounds__(256) void k_hist2(const int* __restrict__ out_idx,
                                               int* __restrict__ cnt) {
    int i = blockIdx.x * 256 + threadIdx.x;
    if (i < N_IN) atomicAdd(&cnt[out_idx[i]], 1);
}

__global__ __launch_bounds__(256) void k_scan_a(const int* __restrict__ cnt,
                                                int* __restrict__ S,
                                                int* __restrict__ bsum) {
    __shared__ int sh[256];
    int t = threadIdx.x;
    int g = blockIdx.x * 256 + t;
    int v = cnt[g];
    sh[t] = v;
    __syncthreads();
#pragma unroll
    for (int off = 1; off < 256; off <<= 1) {
        int a = (t >= off) ? sh[t - off] : 0;
        __syncthreads();
        sh[t] += a;
        __syncthreads();
    }
    S[g] = sh[t] - v;              // exclusive within block
    if (t == 255) bsum[blockIdx.x] = sh[255];
}

__global__ __launch_bounds__(1024) void k_scan_b(int* __restrict__ bsum) {
    __shared__ int sh[1024];
    int t = threadIdx.x;
    int v = (t < N_SBLK) ? bsum[t] : 0;
    sh[t] = v;
    __syncthreads();
#pragma unroll
    for (int off = 1; off < 1024; off <<= 1) {
        int a = (t >= off) ? sh[t - off] : 0;
        __syncthreads();
        sh[t] += a;
        __syncthreads();
    }
    bsum[t] = sh[t] - v;           // exclusive
}

__global__ __launch_bounds__(256) void k_scan_c(int* __restrict__ S,
                                                const int* __restrict__ bsum) {
    int g = blockIdx.x * 256 + threadIdx.x;
    S[g] += bsum[blockIdx.x];
}

__global__ __launch_bounds__(256) void k_scatter2(const int* __restrict__ out_idx,
                                                  const int* __restrict__ offs,
                                                  int* __restrict__ S,
                                                  int* __restrict__ rlist) {
    int i = blockIdx.x * 256 + threadIdx.x;
    if (i < N_IN) {
        int o = out_idx[i];
        int pos = atomicAdd(&S[o], 1);
        rlist[pos] = i | (offs[i] << 21);
    }
}

// repack weight[k][j][c] -> WG[k][j>>2][c][j&3]  (wave reads are contiguous 1KB)
__global__ __launch_bounds__(256) void k_wt(const float* __restrict__ w,
                                            float* __restrict__ WT) {
    int e = blockIdx.x * 256 + threadIdx.x;   // 16384
    int k = e >> 11, j = (e >> 6) & 31, c = e & 63;
    WT[k * 2048 + (j >> 2) * 256 + c * 4 + (j & 3)] = w[e];
}

__global__ __launch_bounds__(256) void k_gconv(const float* __restrict__ xf,
                                               const int* __restrict__ Sarr,
                                               const int* __restrict__ rlist,
                                               const float* __restrict__ WG,
                                               float* __restrict__ out) {
    int lane = threadIdx.x & 63;
    int wv = threadIdx.x >> 6;
    int group = blockIdx.x * 4 + wv;
    if (group >= N_GROUPS) return;
    int base = group * 8;
    int kq = lane >> 3, jq = lane & 7;
    int slot = lane >> 3;

    float4 vx[8];
    unsigned km[8];
#pragma unroll
    for (int r = 0; r < 8; ++r) {
        vx[r] = make_float4(0.f, 0.f, 0.f, 0.f);
        km[r] = 0u;
    }

#pragma unroll
    for (int r = 0; r < 8; ++r) {
        int s = Sarr[base + r];
        int e = Sarr[base + r + 1];
        unsigned m = 0;
        for (int p = s; p < e; p += 8) {
            int pp = p + slot;
            if (pp >= e) pp = e - 1;          // clamp; tail slots break before use
            int pkv = rlist[pp];
#pragma unroll
            for (int ss = 0; ss < 8; ++ss) {
                if (p + ss >= e) break;       // uniform
                int pks = __builtin_amdgcn_readlane(pkv, ss * 8);
                int idx = pks & 0x1FFFFF;
                int kp = (pks >> 21) & 7;
                m |= 1u << kp;
                if (kq == kp) {
                    const float4 xq = *(const float4*)(xf + (size_t)idx * 32 + jq * 4);
                    vx[r].x += xq.x; vx[r].y += xq.y;
                    vx[r].z += xq.z; vx[r].w += xq.w;
                }
            }
        }
        km[r] = m;
    }

    unsigned anym = km[0] | km[1] | km[2] | km[3] | km[4] | km[5] | km[6] | km[7];
    float acc[8];
#pragma unroll
    for (int r = 0; r < 8; ++r) acc[r] = 0.f;

    for (int k = 0; k < 8; ++k) {
        if (!((anym >> k) & 1u)) continue;
        const float4* wp = ((const float4*)WG) + k * 512;
        float4 w[8];
#pragma unroll
        for (int q = 0; q < 8; ++q) w[q] = wp[q * 64 + lane];
#pragma unroll
        for (int r = 0; r < 8; ++r) {
            if (!((km[r] >> k) & 1u)) continue;
#pragma unroll
            for (int q = 0; q < 8; ++q) {
                int ls = k * 8 + q;
                float a0 = __int_as_float(__builtin_amdgcn_readlane(__float_as_int(vx[r].x), ls));
                float a1 = __int_as_float(__builtin_amdgcn_readlane(__float_as_int(vx[r].y), ls));
                float a2 = __int_as_float(__builtin_amdgcn_readlane(__float_as_int(vx[r].z), ls));
                float a3 = __int_as_float(__builtin_amdgcn_readlane(__float_as_int(vx[r].w), ls));
                acc[r] = fmaf(a0, w[q].x, acc[r]);
                acc[r] = fmaf(a1, w[q].y, acc[r]);
                acc[r] = fmaf(a2, w[q].z, acc[r]);
                acc[r] = fmaf(a3, w[q].w, acc[r]);
            }
        }
    }

#pragma unroll
    for (int r = 0; r < 8; ++r)
        out[(size_t)(base + r) * 64 + lane] = acc[r];
}

// ==================== shared post-passes (both paths) ====================

__global__ __launch_bounds__(256) void k_stats(const float* __restrict__ out,
                                               float* __restrict__ sums,
                                               float* __restrict__ sumsq) {
    int t = threadIdx.x;
    long stride = (long)gridDim.x * 256;
    float s = 0.f, q = 0.f;
    for (long i = (long)blockIdx.x * 256 + t; i < (long)N_OUT * C_OUT; i += stride) {
        float v = out[i];
        s += v;
        q = fmaf(v, v, q);
    }
    __shared__ float ls[256], lq[256];
    ls[t] = s; lq[t] = q;
    __syncthreads();
    if (t < 64) {
        s = ls[t] + ls[t + 64] + ls[t + 128] + ls[t + 192];
        q = lq[t] + lq[t + 64] + lq[t + 128] + lq[t + 192];
        atomicAdd(&sums[t], s);
        atomicAdd(&sumsq[t], q);
    }
}

__global__ void k_ctx(const float* __restrict__ context,
                      const float* __restrict__ ctx_w,
                      float* __restrict__ ctx_out) {
    int t = threadIdx.x;  // 128
    float s = 0.f;
    for (int r = 0; r < 256; ++r) s = fmaf(context[r], ctx_w[r * 128 + t], s);
    ctx_out[t] = s;
}

__global__ void k_prep(const float* __restrict__ sums, const float* __restrict__ sumsq,
                       const float* __restrict__ gamma, const float* __restrict__ beta,
                       const int* __restrict__ cond, const float* __restrict__ ctx_out,
                       float* __restrict__ AB) {
    int c = threadIdx.x;  // 64
    float mean = sums[c] * (1.f / N_OUT);
    float var  = sumsq[c] * (1.f / N_OUT) - mean * mean;
    float inv  = rsqrtf(var + EPS);
    int cd = cond[0];
    float g = gamma[cd * C_OUT + c], b = beta[cd * C_OUT + c];
    float sc = 1.f + ctx_out[c];
    float sh = ctx_out[64 + c];
    AB[c]      = inv * g * sc;
    AB[64 + c] = (b - mean * inv * g) * sc + sh;
}

__global__ __launch_bounds__(256) void k_norm(float* __restrict__ out,
                                              const float* __restrict__ AB) {
    __shared__ float4 lA[16], lB[16];
    int t = threadIdx.x;
    if (t < 16) {
        lA[t] = ((const float4*)AB)[t];
        lB[t] = ((const float4*)AB)[16 + t];
    }
    __syncthreads();
    const long total4 = (long)N_OUT * C_OUT / 4;
    long stride = (long)gridDim.x * 256;
    for (long i = (long)blockIdx.x * 256 + t; i < total4; i += stride) {
        float4 v = ((float4*)out)[i];
        float4 a = lA[i & 15], b = lB[i & 15];
        v.x = fmaxf(fmaf(v.x, a.x, b.x), 0.f);
        v.y = fmaxf(fmaf(v.y, a.y, b.y), 0.f);
        v.z = fmaxf(fmaf(v.z, a.z, b.z), 0.f);
        v.w = fmaxf(fmaf(v.w, a.w, b.w), 0.f);
        ((float4*)out)[i] = v;
    }
}

// ================= fallback path (round-1, validated) =================
#define FB_HIST   0
#define FB_BSTART 8
#define FB_CURSOR 16
#define FB_SUMS   (128/4)
#define FB_SUMSQ  (384/4)
#define FB_CTX    (640/4)
#define FB_AB     (1152/4)
#define FB_PERM_BYTES 8192
#define FB_CONV_BLOCKS 7821
#define FB_PERM_CAP (FB_CONV_BLOCKS*256)

__global__ __launch_bounds__(256) void k_hist_fb(const int* __restrict__ offs,
                                                 int* __restrict__ hist) {
    __shared__ int lh[K_VOL];
    int t = threadIdx.x;
    if (t < K_VOL) lh[t] = 0;
    __syncthreads();
    int i4 = blockIdx.x * 256 + t;
    if (i4 < N_IN / 4) {
        int4 v = ((const int4*)offs)[i4];
        atomicAdd(&lh[v.x], 1); atomicAdd(&lh[v.y], 1);
        atomicAdd(&lh[v.z], 1); atomicAdd(&lh[v.w], 1);
    }
    __syncthreads();
    if (t < K_VOL) atomicAdd(&hist[t], lh[t]);
}

__global__ void k_scan_fb(int* __restrict__ wsi) {
    if (threadIdx.x == 0) {
        int s = 0;
        for (int k = 0; k < K_VOL; ++k) {
            wsi[FB_BSTART + k] = s;
            wsi[FB_CURSOR + k] = s;
            s += (wsi[FB_HIST + k] + 255) & ~255;
        }
    }
}

__global__ __launch_bounds__(256) void k_scatter_fb(const int* __restrict__ offs,
                                                    int* __restrict__ cursor,
                                                    int* __restrict__ perm) {
    __shared__ int lcnt[K_VOL];
    __shared__ int lbase[K_VOL];
    int t = threadIdx.x;
    if (t < K_VOL) lcnt[t] = 0;
    __syncthreads();
    int i = blockIdx.x * 256 + t;
    int k = 0, lpos = 0;
    bool valid = i < N_IN;
    if (valid) { k = offs[i]; lpos = atomicAdd(&lcnt[k], 1); }
    __syncthreads();
    if (t < K_VOL && lcnt[t] > 0) lbase[t] = atomicAdd(&cursor[t], lcnt[t]);
    __syncthreads();
    if (valid) perm[lbase[k] + lpos] = i;
}

__global__ __launch_bounds__(256) void k_conv_fb(const float* __restrict__ in_feats,
                                                 const int* __restrict__ out_idx,
                                                 const float* __restrict__ weight,
                                                 const int* __restrict__ bstart,
                                                 const int* __restrict__ perm,
                                                 float* __restrict__ out) {
    int p = blockIdx.x * 256 + threadIdx.x;
    int p0 = blockIdx.x * 256;
    int k = 0;
#pragma unroll
    for (int t = 1; t < K_VOL; ++t)
        if (p0 >= bstart[t]) k = t;
    k = __builtin_amdgcn_readfirstlane(k);
    const float4* __restrict__ Wk = (const float4*)(weight + (size_t)k * (C_IN * C_OUT));

    int idx = perm[p];
    bool valid = idx >= 0;

    float4 xv[8];
#pragma unroll
    for (int q = 0; q < 8; ++q) xv[q] = make_float4(0.f, 0.f, 0.f, 0.f);
    if (valid) {
        const float4* xr = (const float4*)(in_feats + (size_t)idx * C_IN);
#pragma unroll
        for (int q = 0; q < 8; ++q) xv[q] = xr[q];
    }

    float4 acc[16];
#pragma unroll
    for (int c = 0; c < 16; ++c) acc[c] = make_float4(0.f, 0.f, 0.f, 0.f);

#pragma unroll
    for (int j = 0; j < C_IN; ++j) {
        const float4 xq = xv[j >> 2];
        const float xj = ((j & 3) == 0) ? xq.x : ((j & 3) == 1) ? xq.y
                        : ((j & 3) == 2) ? xq.z : xq.w;
#pragma unroll
        for (int c = 0; c < 16; ++c) {
            const float4 w = Wk[j * 16 + c];
            acc[c].x = fmaf(xj, w.x, acc[c].x);
            acc[c].y = fmaf(xj, w.y, acc[c].y);
            acc[c].z = fmaf(xj, w.z, acc[c].z);
            acc[c].w = fmaf(xj, w.w, acc[c].w);
        }
    }

    if (valid) {
        float* op = out + (size_t)out_idx[idx] * C_OUT;
#pragma unroll
        for (int c = 0; c < 16; ++c) {
            atomicAdd(op + 4 * c + 0, acc[c].x);
            atomicAdd(op + 4 * c + 1, acc[c].y);
            atomicAdd(op + 4 * c + 2, acc[c].z);
            atomicAdd(op + 4 * c + 3, acc[c].w);
        }
    }
}

// ============================== launch ==============================

extern "C" void kernel_launch(void* const* d_in, const int* in_sizes, int n_in,
                              void* d_out, int out_size, void* d_ws, size_t ws_size,
                              hipStream_t stream) {
    const float* in_feats = (const float*)d_in[0];
    const int*   offs     = (const int*)d_in[1];
    const int*   out_idx  = (const int*)d_in[2];
    const float* weight   = (const float*)d_in[3];
    const float* gamma    = (const float*)d_in[4];
    const float* beta     = (const float*)d_in[5];
    const float* context  = (const float*)d_in[6];
    const float* ctx_w    = (const float*)d_in[7];
    const int*   cond     = (const int*)d_in[8];
    float* out = (float*)d_out;

    int*   wsi = (int*)d_ws;
    float* wsf = (float*)d_ws;

    if (ws_size >= FP_NEED_BYTES) {
        // ---------------- fast path: CSR gather conv ----------------
        int*   S_base = wsi + 1;
        float* WT     = wsf + FP_WT;
        int*   bsum   = wsi + FP_BSUM;
        float* smalls = wsf + FP_SMALL;          // sums,sumsq,ctx,AB
        int*   rlist  = wsi + FP_RLIST;
        int*   cnt    = rlist;                   // alias (dead after scan)

        hipMemsetAsync(wsi, 0, 4, stream);                       // S anchor
        hipMemsetAsync(cnt, 0, (size_t)N_SCAN * 4, stream);
        hipMemsetAsync(smalls, 0, 384 * 4, stream);

        k_hist2<<<PT_BLOCKS, 256, 0, stream>>>(out_idx, cnt);
        k_scan_a<<<N_SBLK, 256, 0, stream>>>(cnt, S_base, bsum);
        k_scan_b<<<1, 1024, 0, stream>>>(bsum);
        k_scan_c<<<N_SBLK, 256, 0, stream>>>(S_base, bsum);
        k_wt<<<64, 256, 0, stream>>>(weight, WT);
        k_scatter2<<<PT_BLOCKS, 256, 0, stream>>>(out_idx, offs, S_base, rlist);
        k_gconv<<<GCONV_BLOCKS, 256, 0, stream>>>(in_feats, wsi, rlist, WT, out);

        k_stats<<<2048, 256, 0, stream>>>(out, smalls, smalls + 64);
        k_ctx<<<1, 128, 0, stream>>>(context, ctx_w, smalls + 128);
        k_prep<<<1, 64, 0, stream>>>(smalls, smalls + 64, gamma, beta,
                                     cond, smalls + 128, smalls + 256);
        k_norm<<<2048, 256, 0, stream>>>(out, smalls + 256);
    } else {
        // ---------------- fallback: round-1 (validated) ----------------
        int* perm = (int*)((char*)d_ws + FB_PERM_BYTES);

        hipMemsetAsync(d_out, 0, (size_t)N_OUT * C_OUT * sizeof(float), stream);
        hipMemsetAsync(d_ws, 0, FB_PERM_BYTES, stream);
        hipMemsetAsync(perm, 0xFF, (size_t)FB_PERM_CAP * sizeof(int), stream);

        k_hist_fb<<<(N_IN / 4 + 255) / 256, 256, 0, stream>>>(offs, wsi + FB_HIST);
        k_scan_fb<<<1, 1, 0, stream>>>(wsi);
        k_scatter_fb<<<(N_IN + 255) / 256, 256, 0, stream>>>(offs, wsi + FB_CURSOR, perm);
        k_conv_fb<<<FB_CONV_BLOCKS, 256, 0, stream>>>(in_feats, out_idx, weight,
                                                      wsi + FB_BSTART, perm, out);
        k_stats<<<2048, 256, 0, stream>>>(out, wsf + FB_SUMS, wsf + FB_SUMSQ);
        k_ctx<<<1, 128, 0, stream>>>(context, ctx_w, wsf + FB_CTX);
        k_prep<<<1, 64, 0, stream>>>(wsf + FB_SUMS, wsf + FB_SUMSQ, gamma, beta,
                                     cond, wsf + FB_CTX, wsf + FB_AB);
        k_norm<<<2048, 256, 0, stream>>>(out, wsf + FB_AB);
    }
}

// Round 3
// 673.415 us; speedup vs baseline: 10.5173x; 1.1707x over previous
//
#include <hip/hip_runtime.h>

#define N_IN 2000000
#define N_OUT 250000
#define C_IN 32
#define C_OUT 64
#define K_VOL 8
#define EPS 1e-5f
#define CAP 32

#define N_GROUPS 31250         // N_OUT/8
#define GCONV_BLOCKS 7813      // ceil(31250/4)
#define PT_BLOCKS 7813         // ceil(N_IN/256)

// ======== tier-1 workspace layout (int units) ========
// [0 .. 249999]        cnt[250000]
// [250000 .. 266383]   WT (quad-packed weights, 16384 floats)
// [266384 .. 266767]   smalls: sums[64], sumsq[64], ctx[128], AB[128]
// [266768 .. 8266767]  rlist[250000*32]
#define T1_WT     250000
#define T1_SMALL  266384
#define T1_RLIST  266768
#define T1_NEED_BYTES ((size_t)(T1_RLIST + N_OUT * CAP) * 4)   // ~33.1 MB

// ======== tier-2 (round-2 CSR) workspace layout ========
#define FP_WT        250368
#define FP_BSUM      266752
#define FP_SMALL     267776
#define FP_RLIST     268288
#define FP_NEED_BYTES ((size_t)(FP_RLIST + N_IN) * 4)   // ~9.07 MB
#define N_SCAN 250112
#define N_SBLK 977

// ==================== shared: weight repack ====================
// weight[k][j][c] -> WT[k*2048 + (j>>2)*256 + c*4 + (j&3)]
__global__ __launch_bounds__(256) void k_wt(const float* __restrict__ w,
                                            float* __restrict__ WT) {
    int e = blockIdx.x * 256 + threadIdx.x;   // 16384
    int k = e >> 11, j = (e >> 6) & 31, c = e & 63;
    WT[k * 2048 + (j >> 2) * 256 + c * 4 + (j & 3)] = w[e];
}

// ==================== tier-1 kernels ====================

__global__ __launch_bounds__(256) void k_scat(const int* __restrict__ out_idx,
                                              const int* __restrict__ offs,
                                              int* __restrict__ cnt,
                                              int* __restrict__ rlist) {
    int i = blockIdx.x * 256 + threadIdx.x;
    if (i < N_IN) {
        int o = out_idx[i];
        int pos = atomicAdd(&cnt[o], 1);
        if (pos < CAP) rlist[o * CAP + pos] = i | (offs[i] << 21);
    }
}

// One wave = 8 output rows. Build: LDS accumulator VX[r][j*9+k] (+2-way banks).
// GEMM: identical readlane structure to the validated round-2 kernel.
__global__ __launch_bounds__(256) void k_gconv2(const float* __restrict__ xf,
                                                const int* __restrict__ cnt,
                                                const int* __restrict__ rlist,
                                                const float* __restrict__ WG,
                                                float* __restrict__ out) {
    __shared__ float vxl[4 * 2312];
    int lane = threadIdx.x & 63;
    int wv = threadIdx.x >> 6;
    int group = blockIdx.x * 4 + wv;
    if (group >= N_GROUPS) return;           // no __syncthreads below: safe
    float* VX = vxl + wv * 2312;
    int* MKi = (int*)(VX + 2304);
    int base = group * 8;
    int slot = lane >> 3;                    // build: point slot ; gemm: kq
    int jq = lane & 7;

    // ---- zero accumulators + masks (per-wave private; DS in-order) ----
    float4* z4 = (float4*)VX;
#pragma unroll
    for (int i = 0; i < 9; ++i) z4[i * 64 + lane] = make_float4(0.f, 0.f, 0.f, 0.f);
    if (lane < 8) MKi[lane] = 0;

    // ---- prefetch counts + first two point-batches for all 8 rows ----
    int cv = cnt[base + slot];
    int pkA = rlist[(base + slot) * CAP + jq];
    int pkB = rlist[(base + slot) * CAP + 8 + jq];

#pragma unroll
    for (int r = 0; r < 8; ++r) {
        int cr = __builtin_amdgcn_readlane(cv, r * 8);
        if (cr > CAP) cr = CAP;
        int hi = cr - 1; if (hi < 0) hi = 0;
        // ---- batch 0 (slots 0..7), straight-line ----
        {
            int pk = __shfl(pkA, r * 8 + slot, 64);
            int idx = pk & 0x1FFFFF; if (idx > N_IN - 1) idx = N_IN - 1;
            int kp = (pk >> 21) & 7;
            const float4 x = *(const float4*)(xf + (size_t)idx * 32 + jq * 4);
            float* dst = VX + r * 288 + jq * 36 + kp;
            if (slot < cr) {
                atomicAdd(dst + 0,  x.x);
                atomicAdd(dst + 9,  x.y);
                atomicAdd(dst + 18, x.z);
                atomicAdd(dst + 27, x.w);
                if (jq == 0) atomicOr(&MKi[r], 1 << kp);
            }
        }
        // ---- batch 1 (slots 8..15), straight-line, clamped ----
        {
            int q = 8 + slot; if (q > hi) q = hi;
            int pk1 = __shfl(pkA, r * 8 + (q & 7), 64);
            int pk2 = __shfl(pkB, r * 8 + (q & 7), 64);
            int pk = (q < 8) ? pk1 : pk2;
            int idx = pk & 0x1FFFFF; if (idx > N_IN - 1) idx = N_IN - 1;
            int kp = (pk >> 21) & 7;
            const float4 x = *(const float4*)(xf + (size_t)idx * 32 + jq * 4);
            float* dst = VX + r * 288 + jq * 36 + kp;
            if (8 + slot < cr) {
                atomicAdd(dst + 0,  x.x);
                atomicAdd(dst + 9,  x.y);
                atomicAdd(dst + 18, x.z);
                atomicAdd(dst + 27, x.w);
                if (jq == 0) atomicOr(&MKi[r], 1 << kp);
            }
        }
        // ---- batches 2+ (cr > 16: ~0.4% of rows) ----
        if (cr > 16) {
            for (int p0 = 16; p0 < cr; p0 += 8) {
                int pp = p0 + slot; if (pp > hi) pp = hi;
                int pk = rlist[(base + r) * CAP + pp];
                int idx = pk & 0x1FFFFF; if (idx > N_IN - 1) idx = N_IN - 1;
                int kp = (pk >> 21) & 7;
                const float4 x = *(const float4*)(xf + (size_t)idx * 32 + jq * 4);
                float* dst = VX + r * 288 + jq * 36 + kp;
                if (p0 + slot < cr) {
                    atomicAdd(dst + 0,  x.x);
                    atomicAdd(dst + 9,  x.y);
                    atomicAdd(dst + 18, x.z);
                    atomicAdd(dst + 27, x.w);
                    if (jq == 0) atomicOr(&MKi[r], 1 << kp);
                }
            }
        }
    }

    // drain LDS atomics; block compiler reordering of the reads below
    asm volatile("s_waitcnt lgkmcnt(0)" ::: "memory");

    // ---- readback into round-2 (kq,jq) register layout ----
    float4 vxr[8];
    int km[8];
#pragma unroll
    for (int r = 0; r < 8; ++r) {
        const float* src = VX + r * 288 + jq * 36 + slot;   // slot == kq here
        float4 v;
        v.x = src[0]; v.y = src[9]; v.z = src[18]; v.w = src[27];
        vxr[r] = v;
        km[r] = __builtin_amdgcn_readfirstlane(MKi[r]);
    }

    int anym = km[0] | km[1] | km[2] | km[3] | km[4] | km[5] | km[6] | km[7];
    float acc[8];
#pragma unroll
    for (int r = 0; r < 8; ++r) acc[r] = 0.f;

    for (int k = 0; k < 8; ++k) {
        if (!((anym >> k) & 1)) continue;
        const float4* wp = ((const float4*)WG) + k * 512;
        float4 w[8];
#pragma unroll
        for (int q = 0; q < 8; ++q) w[q] = wp[q * 64 + lane];
#pragma unroll
        for (int r = 0; r < 8; ++r) {
            if (!((km[r] >> k) & 1)) continue;
#pragma unroll
            for (int q = 0; q < 8; ++q) {
                int ls = k * 8 + q;
                float a0 = __int_as_float(__builtin_amdgcn_readlane(__float_as_int(vxr[r].x), ls));
                float a1 = __int_as_float(__builtin_amdgcn_readlane(__float_as_int(vxr[r].y), ls));
                float a2 = __int_as_float(__builtin_amdgcn_readlane(__float_as_int(vxr[r].z), ls));
                float a3 = __int_as_float(__builtin_amdgcn_readlane(__float_as_int(vxr[r].w), ls));
                acc[r] = fmaf(a0, w[q].x, acc[r]);
                acc[r] = fmaf(a1, w[q].y, acc[r]);
                acc[r] = fmaf(a2, w[q].z, acc[r]);
                acc[r] = fmaf(a3, w[q].w, acc[r]);
            }
        }
    }

#pragma unroll
    for (int r = 0; r < 8; ++r)
        out[(size_t)(base + r) * 64 + lane] = acc[r];
}

// ==================== shared post-passes ====================

__global__ __launch_bounds__(256) void k_stats(const float* __restrict__ out,
                                               float* __restrict__ sums,
                                               float* __restrict__ sumsq) {
    int t = threadIdx.x;
    long stride = (long)gridDim.x * 256;
    float s = 0.f, q = 0.f;
    for (long i = (long)blockIdx.x * 256 + t; i < (long)N_OUT * C_OUT; i += stride) {
        float v = out[i];
        s += v;
        q = fmaf(v, v, q);
    }
    __shared__ float ls[256], lq[256];
    ls[t] = s; lq[t] = q;
    __syncthreads();
    if (t < 64) {
        s = ls[t] + ls[t + 64] + ls[t + 128] + ls[t + 192];
        q = lq[t] + lq[t + 64] + lq[t + 128] + lq[t + 192];
        atomicAdd(&sums[t], s);
        atomicAdd(&sumsq[t], q);
    }
}

__global__ __launch_bounds__(256) void k_ctx(const float* __restrict__ context,
                                             const float* __restrict__ ctx_w,
                                             float* __restrict__ ctx_out) {
    int t = threadIdx.x;               // 256 threads, 1 block
    int col = t & 127, half = t >> 7;  // 2 row-halves for ILP
    float s = 0.f;
    for (int r = half * 128; r < half * 128 + 128; ++r)
        s = fmaf(context[r], ctx_w[r * 128 + col], s);
    __shared__ float part[256];
    part[t] = s;
    __syncthreads();
    if (t < 128) ctx_out[t] = part[t] + part[t + 128];
}

__global__ void k_prep(const float* __restrict__ sums, const float* __restrict__ sumsq,
                       const float* __restrict__ gamma, const float* __restrict__ beta,
                       const int* __restrict__ cond, const float* __restrict__ ctx_out,
                       float* __restrict__ AB) {
    int c = threadIdx.x;  // 64
    float mean = sums[c] * (1.f / N_OUT);
    float var  = sumsq[c] * (1.f / N_OUT) - mean * mean;
    float inv  = rsqrtf(var + EPS);
    int cd = cond[0];
    float g = gamma[cd * C_OUT + c], b = beta[cd * C_OUT + c];
    float sc = 1.f + ctx_out[c];
    float sh = ctx_out[64 + c];
    AB[c]      = inv * g * sc;
    AB[64 + c] = (b - mean * inv * g) * sc + sh;
}

__global__ __launch_bounds__(256) void k_norm(float* __restrict__ out,
                                              const float* __restrict__ AB) {
    __shared__ float4 lA[16], lB[16];
    int t = threadIdx.x;
    if (t < 16) {
        lA[t] = ((const float4*)AB)[t];
        lB[t] = ((const float4*)AB)[16 + t];
    }
    __syncthreads();
    const long total4 = (long)N_OUT * C_OUT / 4;
    long stride = (long)gridDim.x * 256;
    for (long i = (long)blockIdx.x * 256 + t; i < total4; i += stride) {
        float4 v = ((float4*)out)[i];
        float4 a = lA[i & 15], b = lB[i & 15];
        v.x = fmaxf(fmaf(v.x, a.x, b.x), 0.f);
        v.y = fmaxf(fmaf(v.y, a.y, b.y), 0.f);
        v.z = fmaxf(fmaf(v.z, a.z, b.z), 0.f);
        v.w = fmaxf(fmaf(v.w, a.w, b.w), 0.f);
        ((float4*)out)[i] = v;
    }
}

// ==================== tier-2 (round-2 CSR path, validated) ====================

__global__ __launch_bounds__(256) void k_hist2(const int* __restrict__ out_idx,
                                               int* __restrict__ cnt) {
    int i = blockIdx.x * 256 + threadIdx.x;
    if (i < N_IN) atomicAdd(&cnt[out_idx[i]], 1);
}

__global__ __launch_bounds__(256) void k_scan_a(const int* __restrict__ cnt,
                                                int* __restrict__ S,
                                                int* __restrict__ bsum) {
    __shared__ int sh[256];
    int t = threadIdx.x;
    int g = blockIdx.x * 256 + t;
    int v = cnt[g];
    sh[t] = v;
    __syncthreads();
#pragma unroll
    for (int off = 1; off < 256; off <<= 1) {
        int a = (t >= off) ? sh[t - off] : 0;
        __syncthreads();
        sh[t] += a;
        __syncthreads();
    }
    S[g] = sh[t] - v;
    if (t == 255) bsum[blockIdx.x] = sh[255];
}

__global__ __launch_bounds__(1024) void k_scan_b(int* __restrict__ bsum) {
    __shared__ int sh[1024];
    int t = threadIdx.x;
    int v = (t < N_SBLK) ? bsum[t] : 0;
    sh[t] = v;
    __syncthreads();
#pragma unroll
    for (int off = 1; off < 1024; off <<= 1) {
        int a = (t >= off) ? sh[t - off] : 0;
        __syncthreads();
        sh[t] += a;
        __syncthreads();
    }
    bsum[t] = sh[t] - v;
}

__global__ __launch_bounds__(256) void k_scan_c(int* __restrict__ S,
                                                const int* __restrict__ bsum) {
    int g = blockIdx.x * 256 + threadIdx.x;
    S[g] += bsum[blockIdx.x];
}

__global__ __launch_bounds__(256) void k_scatter2(const int* __restrict__ out_idx,
                                                  const int* __restrict__ offs,
                                                  int* __restrict__ S,
                                                  int* __restrict__ rlist) {
    int i = blockIdx.x * 256 + threadIdx.x;
    if (i < N_IN) {
        int o = out_idx[i];
        int pos = atomicAdd(&S[o], 1);
        rlist[pos] = i | (offs[i] << 21);
    }
}

__global__ __launch_bounds__(256) void k_gconv_c(const float* __restrict__ xf,
                                                 const int* __restrict__ Sarr,
                                                 const int* __restrict__ rlist,
                                                 const float* __restrict__ WG,
                                                 float* __restrict__ out) {
    int lane = threadIdx.x & 63;
    int wv = threadIdx.x >> 6;
    int group = blockIdx.x * 4 + wv;
    if (group >= N_GROUPS) return;
    int base = group * 8;
    int kq = lane >> 3, jq = lane & 7;
    int slot = lane >> 3;

    float4 vx[8];
    unsigned km[8];
#pragma unroll
    for (int r = 0; r < 8; ++r) {
        vx[r] = make_float4(0.f, 0.f, 0.f, 0.f);
        km[r] = 0u;
    }

#pragma unroll
    for (int r = 0; r < 8; ++r) {
        int s = Sarr[base + r];
        int e = Sarr[base + r + 1];
        unsigned m = 0;
        for (int p = s; p < e; p += 8) {
            int pp = p + slot;
            if (pp >= e) pp = e - 1;
            int pkv = rlist[pp];
#pragma unroll
            for (int ss = 0; ss < 8; ++ss) {
                if (p + ss >= e) break;
                int pks = __builtin_amdgcn_readlane(pkv, ss * 8);
                int idx = pks & 0x1FFFFF;
                int kp = (pks >> 21) & 7;
                m |= 1u << kp;
                if (kq == kp) {
                    const float4 xq = *(const float4*)(xf + (size_t)idx * 32 + jq * 4);
                    vx[r].x += xq.x; vx[r].y += xq.y;
                    vx[r].z += xq.z; vx[r].w += xq.w;
                }
            }
        }
        km[r] = m;
    }

    unsigned anym = km[0] | km[1] | km[2] | km[3] | km[4] | km[5] | km[6] | km[7];
    float acc[8];
#pragma unroll
    for (int r = 0; r < 8; ++r) acc[r] = 0.f;

    for (int k = 0; k < 8; ++k) {
        if (!((anym >> k) & 1u)) continue;
        const float4* wp = ((const float4*)WG) + k * 512;
        float4 w[8];
#pragma unroll
        for (int q = 0; q < 8; ++q) w[q] = wp[q * 64 + lane];
#pragma unroll
        for (int r = 0; r < 8; ++r) {
            if (!((km[r] >> k) & 1u)) continue;
#pragma unroll
            for (int q = 0; q < 8; ++q) {
                int ls = k * 8 + q;
                float a0 = __int_as_float(__builtin_amdgcn_readlane(__float_as_int(vx[r].x), ls));
                float a1 = __int_as_float(__builtin_amdgcn_readlane(__float_as_int(vx[r].y), ls));
                float a2 = __int_as_float(__builtin_amdgcn_readlane(__float_as_int(vx[r].z), ls));
                float a3 = __int_as_float(__builtin_amdgcn_readlane(__float_as_int(vx[r].w), ls));
                acc[r] = fmaf(a0, w[q].x, acc[r]);
                acc[r] = fmaf(a1, w[q].y, acc[r]);
                acc[r] = fmaf(a2, w[q].z, acc[r]);
                acc[r] = fmaf(a3, w[q].w, acc[r]);
            }
        }
    }

#pragma unroll
    for (int r = 0; r < 8; ++r)
        out[(size_t)(base + r) * 64 + lane] = acc[r];
}

// ============================== launch ==============================

extern "C" void kernel_launch(void* const* d_in, const int* in_sizes, int n_in,
                              void* d_out, int out_size, void* d_ws, size_t ws_size,
                              hipStream_t stream) {
    const float* in_feats = (const float*)d_in[0];
    const int*   offs     = (const int*)d_in[1];
    const int*   out_idx  = (const int*)d_in[2];
    const float* weight   = (const float*)d_in[3];
    const float* gamma    = (const float*)d_in[4];
    const float* beta     = (const float*)d_in[5];
    const float* context  = (const float*)d_in[6];
    const float* ctx_w    = (const float*)d_in[7];
    const int*   cond     = (const int*)d_in[8];
    float* out = (float*)d_out;

    int*   wsi = (int*)d_ws;
    float* wsf = (float*)d_ws;

    if (ws_size >= T1_NEED_BYTES) {
        // -------- tier-1: padded direct scatter + LDS-routed gather conv --------
        int*   cnt    = wsi;
        float* WT     = wsf + T1_WT;
        float* smalls = wsf + T1_SMALL;
        int*   rlist  = wsi + T1_RLIST;

        hipMemsetAsync(cnt, 0, (size_t)N_OUT * 4, stream);
        hipMemsetAsync(smalls, 0, 384 * 4, stream);

        k_wt<<<64, 256, 0, stream>>>(weight, WT);
        k_scat<<<PT_BLOCKS, 256, 0, stream>>>(out_idx, offs, cnt, rlist);
        k_gconv2<<<GCONV_BLOCKS, 256, 0, stream>>>(in_feats, cnt, rlist, WT, out);

        k_stats<<<2048, 256, 0, stream>>>(out, smalls, smalls + 64);
        k_ctx<<<1, 256, 0, stream>>>(context, ctx_w, smalls + 128);
        k_prep<<<1, 64, 0, stream>>>(smalls, smalls + 64, gamma, beta,
                                     cond, smalls + 128, smalls + 256);
        k_norm<<<2048, 256, 0, stream>>>(out, smalls + 256);
    } else {
        // -------- tier-2: round-2 CSR path (validated) --------
        int*   S_base = wsi + 1;
        float* WT     = wsf + FP_WT;
        int*   bsum   = wsi + FP_BSUM;
        float* smalls = wsf + FP_SMALL;
        int*   rlist  = wsi + FP_RLIST;
        int*   cnt    = rlist;

        hipMemsetAsync(wsi, 0, 4, stream);
        hipMemsetAsync(cnt, 0, (size_t)N_SCAN * 4, stream);
        hipMemsetAsync(smalls, 0, 384 * 4, stream);

        k_hist2<<<PT_BLOCKS, 256, 0, stream>>>(out_idx, cnt);
        k_scan_a<<<N_SBLK, 256, 0, stream>>>(cnt, S_base, bsum);
        k_scan_b<<<1, 1024, 0, stream>>>(bsum);
        k_scan_c<<<N_SBLK, 256, 0, stream>>>(S_base, bsum);
        k_wt<<<64, 256, 0, stream>>>(weight, WT);
        k_scatter2<<<PT_BLOCKS, 256, 0, stream>>>(out_idx, offs, S_base, rlist);
        k_gconv_c<<<GCONV_BLOCKS, 256, 0, stream>>>(in_feats, wsi, rlist, WT, out);

        k_stats<<<2048, 256, 0, stream>>>(out, smalls, smalls + 64);
        k_ctx<<<1, 256, 0, stream>>>(context, ctx_w, smalls + 128);
        k_prep<<<1, 64, 0, stream>>>(smalls, smalls + 64, gamma, beta,
                                     cond, smalls + 128, smalls + 256);
        k_norm<<<2048, 256, 0, stream>>>(out, smalls + 256);
    }
}